// Round 1
// baseline (812.159 us; speedup 1.0000x reference)
//
#include <hip/hip_runtime.h>
#include <stdint.h>

typedef short bf16x8 __attribute__((ext_vector_type(8)));
typedef float f32x4 __attribute__((ext_vector_type(4)));

#define BM 128
#define BN 128
#define BK 64

__device__ __forceinline__ ushort f2bf(float x) {
    uint32_t u = __float_as_uint(x);
    u += 0x7FFFu + ((u >> 16) & 1u);
    return (ushort)(u >> 16);
}

// C[M,N] = A[M,K] * B[N,K]^T, bf16 MFMA 16x16x32, 128x128 tile, 4 waves.
// MODE 0: bf16 out = acc (+bias), optional transposed copy (per-batch [col][row])
// MODE 1: scores: e=exp(tanh(acc)); write E + E^T bf16; atomic rowsum/colsum
// MODE 2: bf16 out = acc / scale[row]
// MODE 3: f32 out = acc + bias[col] + resid[row,col]
template<int MODE, bool A_F32, bool HAS_BIAS, bool WRITE_T>
__global__ __launch_bounds__(256)
void gemm_bt(const void* __restrict__ Aptr_, const ushort* __restrict__ Bptr_,
             void* __restrict__ Cptr_, ushort* __restrict__ CTptr_,
             const float* __restrict__ bias, const float* __restrict__ resid_,
             float* __restrict__ rsum_, float* __restrict__ csum_,
             const float* __restrict__ scale_,
             int M, int N, int K, int lda, int ldb, int ldc,
             long sA, long sB, long sC, long sCT, long sSum,
             int ldct, int rbshift)
{
    __shared__ ushort Alds[BM * BK];
    __shared__ ushort Blds[BN * BK];

    const int z    = blockIdx.z;
    const int m0   = blockIdx.x * BM;
    const int n0   = blockIdx.y * BN;
    const int tid  = threadIdx.x;
    const int lane = tid & 63;
    const int wave = tid >> 6;
    const int wr   = wave >> 1, wc = wave & 1;
    const int g    = lane >> 4, c = lane & 15;

    const ushort* Bp = Bptr_ + z * sB;

    f32x4 acc[4][4] = {};

    for (int kt = 0; kt < K; kt += BK) {
        // ---- stage A and B tiles (reg-staged, XOR-swizzled 16B chunks) ----
        #pragma unroll
        for (int r = 0; r < 4; ++r) {
            const int li  = r * 256 + tid;     // 16B-chunk linear index
            const int row = li >> 3;
            const int ck  = li & 7;
            const int gck = ck ^ (row & 7);    // swizzled source chunk
            if constexpr (A_F32) {
                const float* src = (const float*)Aptr_ + z * sA + (long)(m0 + row) * lda + kt + gck * 8;
                const float4 f0 = *(const float4*)(src);
                const float4 f1 = *(const float4*)(src + 4);
                uint4 w;
                w.x = (uint)f2bf(f0.x) | ((uint)f2bf(f0.y) << 16);
                w.y = (uint)f2bf(f0.z) | ((uint)f2bf(f0.w) << 16);
                w.z = (uint)f2bf(f1.x) | ((uint)f2bf(f1.y) << 16);
                w.w = (uint)f2bf(f1.z) | ((uint)f2bf(f1.w) << 16);
                *(uint4*)&Alds[li * 8] = w;
            } else {
                const ushort* src = (const ushort*)Aptr_ + z * sA + (long)(m0 + row) * lda + kt + gck * 8;
                *(uint4*)&Alds[li * 8] = *(const uint4*)src;
            }
            const ushort* srcb = Bp + (long)(n0 + row) * ldb + kt + gck * 8;
            *(uint4*)&Blds[li * 8] = *(const uint4*)srcb;
        }
        __syncthreads();
        #pragma unroll
        for (int kk = 0; kk < 2; ++kk) {
            bf16x8 af[4], bfr[4];
            #pragma unroll
            for (int mi = 0; mi < 4; ++mi) {
                const int row = wr * 64 + mi * 16 + c;
                const int ckq = (kk * 4 + g) ^ (row & 7);
                af[mi] = *(const bf16x8*)&Alds[row * BK + ckq * 8];
            }
            #pragma unroll
            for (int ni = 0; ni < 4; ++ni) {
                const int row = wc * 64 + ni * 16 + c;
                const int ckq = (kk * 4 + g) ^ (row & 7);
                bfr[ni] = *(const bf16x8*)&Blds[row * BK + ckq * 8];
            }
            #pragma unroll
            for (int mi = 0; mi < 4; ++mi)
                #pragma unroll
                for (int ni = 0; ni < 4; ++ni)
                    acc[mi][ni] = __builtin_amdgcn_mfma_f32_16x16x32_bf16(af[mi], bfr[ni], acc[mi][ni], 0, 0, 0);
        }
        __syncthreads();
    }

    // ---- epilogues ----
    if constexpr (MODE == 0) {
        ushort* Cp = (ushort*)Cptr_ + z * sC;
        #pragma unroll
        for (int mi = 0; mi < 4; ++mi) {
            const int row = m0 + wr * 64 + mi * 16 + g * 4;
            #pragma unroll
            for (int ni = 0; ni < 4; ++ni) {
                const int col = n0 + wc * 64 + ni * 16 + c;
                const float bv = HAS_BIAS ? bias[col] : 0.f;
                ushort v[4];
                #pragma unroll
                for (int r = 0; r < 4; ++r) v[r] = f2bf(acc[mi][ni][r] + bv);
                #pragma unroll
                for (int r = 0; r < 4; ++r) Cp[(long)(row + r) * ldc + col] = v[r];
                if constexpr (WRITE_T) {
                    const int bb = row >> rbshift;
                    const int ii = row & ((1 << rbshift) - 1);
                    *(ushort4*)&CTptr_[(long)bb * sCT + (long)col * ldct + ii] =
                        make_ushort4(v[0], v[1], v[2], v[3]);
                }
            }
        }
    } else if constexpr (MODE == 1) {
        ushort* Ep  = (ushort*)Cptr_ + z * sC;
        ushort* ETp = CTptr_ + z * sCT;
        float* rs = rsum_ + z * sSum;
        float* cs = csum_ + z * sSum;
        float rowpart[4][4] = {};
        float colpart[4] = {};
        #pragma unroll
        for (int mi = 0; mi < 4; ++mi) {
            const int row = m0 + wr * 64 + mi * 16 + g * 4;
            #pragma unroll
            for (int ni = 0; ni < 4; ++ni) {
                const int col = n0 + wc * 64 + ni * 16 + c;
                ushort v[4];
                #pragma unroll
                for (int r = 0; r < 4; ++r) {
                    const float s = acc[mi][ni][r];
                    const float t = 1.f - 2.f / (__expf(2.f * s) + 1.f);  // tanh(s)
                    const float e = __expf(t);
                    rowpart[mi][r] += e;
                    colpart[ni]    += e;
                    v[r] = f2bf(e);
                }
                #pragma unroll
                for (int r = 0; r < 4; ++r) Ep[(long)(row + r) * ldc + col] = v[r];
                *(ushort4*)&ETp[(long)col * ldct + row] = make_ushort4(v[0], v[1], v[2], v[3]);
            }
        }
        #pragma unroll
        for (int mi = 0; mi < 4; ++mi) {
            #pragma unroll
            for (int r = 0; r < 4; ++r) {
                float v = rowpart[mi][r];
                v += __shfl_xor(v, 1); v += __shfl_xor(v, 2);
                v += __shfl_xor(v, 4); v += __shfl_xor(v, 8);
                if (c == 0) atomicAdd(&rs[m0 + wr * 64 + mi * 16 + g * 4 + r], v);
            }
        }
        #pragma unroll
        for (int ni = 0; ni < 4; ++ni) {
            float v = colpart[ni];
            v += __shfl_xor(v, 16); v += __shfl_xor(v, 32);
            if (g == 0) atomicAdd(&cs[n0 + wc * 64 + ni * 16 + c], v);
        }
    } else if constexpr (MODE == 2) {
        const float* sc = scale_ + z * sSum;
        ushort* Cp = (ushort*)Cptr_ + z * sC;
        #pragma unroll
        for (int mi = 0; mi < 4; ++mi) {
            const int row = m0 + wr * 64 + mi * 16 + g * 4;
            float rcp[4];
            #pragma unroll
            for (int r = 0; r < 4; ++r) rcp[r] = 1.f / sc[row + r];
            #pragma unroll
            for (int ni = 0; ni < 4; ++ni) {
                const int col = n0 + wc * 64 + ni * 16 + c;
                #pragma unroll
                for (int r = 0; r < 4; ++r)
                    Cp[(long)(row + r) * ldc + col] = f2bf(acc[mi][ni][r] * rcp[r]);
            }
        }
    } else { // MODE == 3
        float* Co = (float*)Cptr_;
        #pragma unroll
        for (int mi = 0; mi < 4; ++mi) {
            const int row = m0 + wr * 64 + mi * 16 + g * 4;
            #pragma unroll
            for (int ni = 0; ni < 4; ++ni) {
                const int col = n0 + wc * 64 + ni * 16 + c;
                const float bv = bias[col];
                #pragma unroll
                for (int r = 0; r < 4; ++r) {
                    const long idx = (long)(row + r) * ldc + col;
                    Co[idx] = acc[mi][ni][r] + bv + resid_[idx];
                }
            }
        }
    }
}

// f32 [R][C] -> bf16 [C][R]
__global__ __launch_bounds__(256)
void tcast(const float* __restrict__ in, ushort* __restrict__ out, int R, int C) {
    __shared__ float t[32][33];
    const int bx = blockIdx.x * 32, by = blockIdx.y * 32;
    const int tx = threadIdx.x, ty = threadIdx.y; // (32, 8)
    for (int i = ty; i < 32; i += 8) {
        const int r = by + i, cc = bx + tx;
        if (r < R && cc < C) t[i][tx] = in[(long)r * C + cc];
    }
    __syncthreads();
    for (int i = ty; i < 32; i += 8) {
        const int cc = bx + i, r = by + tx;
        if (cc < C && r < R) out[(long)cc * R + r] = f2bf(t[tx][i]);
    }
}

// in-place LayerNorm, one row per block
template<int D>
__global__ __launch_bounds__(256)
void ln_rows(float* __restrict__ y, const float* __restrict__ gam, const float* __restrict__ bet) {
    constexpr int NV = D / 256;
    const long row = blockIdx.x;
    float* p = y + row * D;
    const int tid = threadIdx.x;
    float v[NV];
    float s = 0.f, s2 = 0.f;
    #pragma unroll
    for (int k = 0; k < NV; ++k) {
        v[k] = p[tid + k * 256];
        s += v[k]; s2 += v[k] * v[k];
    }
    #pragma unroll
    for (int off = 1; off < 64; off <<= 1) {
        s  += __shfl_xor(s, off);
        s2 += __shfl_xor(s2, off);
    }
    __shared__ float ws[4], ws2[4];
    const int wave = tid >> 6, lane = tid & 63;
    if (lane == 0) { ws[wave] = s; ws2[wave] = s2; }
    __syncthreads();
    s  = ws[0] + ws[1] + ws[2] + ws[3];
    s2 = ws2[0] + ws2[1] + ws2[2] + ws2[3];
    const float mu  = s / D;
    const float var = s2 / D - mu * mu;
    const float rstd = rsqrtf(var + 1e-5f);
    #pragma unroll
    for (int k = 0; k < NV; ++k) {
        const int i = tid + k * 256;
        p[i] = (v[k] - mu) * rstd * gam[i] + bet[i];
    }
}

extern "C" void kernel_launch(void* const* d_in, const int* in_sizes, int n_in,
                              void* d_out, int out_size, void* d_ws, size_t ws_size,
                              hipStream_t stream)
{
    (void)in_sizes; (void)n_in; (void)out_size; (void)ws_size;
    const float* z_a    = (const float*)d_in[0];
    const float* z_b    = (const float*)d_in[1];
    const float* Wa     = (const float*)d_in[2];
    const float* ba     = (const float*)d_in[3];
    const float* Wb     = (const float*)d_in[4];
    const float* bb     = (const float*)d_in[5];
    const float* Wco    = (const float*)d_in[6];
    const float* Woa    = (const float*)d_in[7];
    const float* boa    = (const float*)d_in[8];
    const float* Wob    = (const float*)d_in[9];
    const float* bob    = (const float*)d_in[10];
    const float* ga     = (const float*)d_in[11];
    const float* beta_a = (const float*)d_in[12];
    const float* gb     = (const float*)d_in[13];
    const float* beta_b = (const float*)d_in[14];

    const int Bn = 16, LA = 2048, LB = 2048, DA = 768, DB = 512, DH = 512;
    const long MA = (long)Bn * LA;  // 32768 flattened rows for a-side
    const long MB = (long)Bn * LB;

    char* w = (char*)d_ws;
    size_t off = 0;
    auto alc = [&](size_t bytes) { void* p = w + off; off += (bytes + 255) & ~(size_t)255; return p; };

    ushort* WaT  = (ushort*)alc((size_t)DH * DA * 2);
    ushort* WbT  = (ushort*)alc((size_t)DH * DB * 2);
    ushort* WcoT = (ushort*)alc((size_t)DH * DH * 2);
    ushort* WoaT = (ushort*)alc((size_t)DA * DH * 2);
    ushort* WobT = (ushort*)alc((size_t)DB * DH * 2);
    ushort* h_a  = (ushort*)alc((size_t)MA * DH * 2);
    ushort* h_b  = (ushort*)alc((size_t)MB * DH * 2);
    ushort* h_aT = (ushort*)alc((size_t)Bn * DH * LA * 2);
    ushort* h_bT = (ushort*)alc((size_t)Bn * DH * LB * 2);
    ushort* Ma   = (ushort*)alc((size_t)MA * DH * 2);
    ushort* E    = (ushort*)alc((size_t)Bn * LA * LB * 2);
    ushort* ET   = (ushort*)alc((size_t)Bn * LB * LA * 2);
    ushort* Pa   = (ushort*)alc((size_t)MA * DH * 2);
    ushort* Pb   = (ushort*)alc((size_t)MB * DH * 2);
    float*  rsum = (float*)alc((size_t)Bn * LA * 4);
    float*  csum = (float*)alc((size_t)Bn * LB * 4);

    dim3 blk(256, 1, 1);
    dim3 tb(32, 8, 1);

    // weight transposes (f32 -> bf16, [K][N] -> [N][K])
    tcast<<<dim3(DH / 32, DA / 32, 1), tb, 0, stream>>>(Wa,  WaT,  DA, DH);
    tcast<<<dim3(DH / 32, DB / 32, 1), tb, 0, stream>>>(Wb,  WbT,  DB, DH);
    tcast<<<dim3(DH / 32, DH / 32, 1), tb, 0, stream>>>(Wco, WcoT, DH, DH);
    tcast<<<dim3(DA / 32, DH / 32, 1), tb, 0, stream>>>(Woa, WoaT, DH, DA);
    tcast<<<dim3(DB / 32, DH / 32, 1), tb, 0, stream>>>(Wob, WobT, DH, DB);

    // zero softmax denominators (rsum & csum are contiguous)
    hipMemsetAsync(rsum, 0, (size_t)Bn * (LA + LB) * sizeof(float), stream);

    // h_a = z_a @ Wa + ba   (also writes h_aT per batch)
    gemm_bt<0, true, true, true><<<dim3(MA / BM, DH / BN, 1), blk, 0, stream>>>(
        z_a, WaT, h_a, h_aT, ba, nullptr, nullptr, nullptr, nullptr,
        (int)MA, DH, DA, DA, DA, DH, 0, 0, 0, (long)DH * LA, 0, LA, 11);

    // h_b = z_b @ Wb + bb   (also writes h_bT per batch)
    gemm_bt<0, true, true, true><<<dim3(MB / BM, DH / BN, 1), blk, 0, stream>>>(
        z_b, WbT, h_b, h_bT, bb, nullptr, nullptr, nullptr, nullptr,
        (int)MB, DH, DB, DB, DB, DH, 0, 0, 0, (long)DH * LB, 0, LB, 11);

    // Ma = h_a @ W_co
    gemm_bt<0, false, false, false><<<dim3(MA / BM, DH / BN, 1), blk, 0, stream>>>(
        h_a, WcoT, Ma, nullptr, nullptr, nullptr, nullptr, nullptr, nullptr,
        (int)MA, DH, DH, DH, DH, DH, 0, 0, 0, 0, 0, 0, 0);

    // scores: E = exp(tanh(Ma @ h_b^T)), E^T, rowsum, colsum  (batched)
    gemm_bt<1, false, false, false><<<dim3(LA / BM, LB / BN, Bn), blk, 0, stream>>>(
        Ma, h_b, E, ET, nullptr, nullptr, rsum, csum, nullptr,
        LA, LB, DH, DH, DH, LB,
        (long)LA * DH, (long)LB * DH, (long)LA * LB, (long)LB * LA, LA, LA, 0);

    // Pa = (E @ h_b) / rowsum  (batched)
    gemm_bt<2, false, false, false><<<dim3(LA / BM, DH / BN, Bn), blk, 0, stream>>>(
        E, h_bT, Pa, nullptr, nullptr, nullptr, nullptr, nullptr, rsum,
        LA, DH, LB, LB, LB, DH,
        (long)LA * LB, (long)DH * LB, (long)LA * DH, 0, LA, 0, 0);

    // Pb = (E^T @ h_a) / colsum  (batched)
    gemm_bt<2, false, false, false><<<dim3(LB / BM, DH / BN, Bn), blk, 0, stream>>>(
        ET, h_aT, Pb, nullptr, nullptr, nullptr, nullptr, nullptr, csum,
        LB, DH, LA, LA, LA, DH,
        (long)LB * LA, (long)DH * LA, (long)LB * DH, 0, LB, 0, 0);

    float* outA = (float*)d_out;
    float* outB = outA + MA * DA;

    // z_a_pre = Pa @ Woa + boa + z_a  -> d_out (f32, in place for LN)
    gemm_bt<3, false, true, false><<<dim3(MA / BM, DA / BN, 1), blk, 0, stream>>>(
        Pa, WoaT, outA, nullptr, boa, z_a, nullptr, nullptr, nullptr,
        (int)MA, DA, DH, DH, DH, DA, 0, 0, 0, 0, 0, 0, 0);

    // z_b_pre = Pb @ Wob + bob + z_b  -> d_out
    gemm_bt<3, false, true, false><<<dim3(MB / BM, DB / BN, 1), blk, 0, stream>>>(
        Pb, WobT, outB, nullptr, bob, z_b, nullptr, nullptr, nullptr,
        (int)MB, DB, DH, DH, DH, DB, 0, 0, 0, 0, 0, 0, 0);

    // LayerNorms in place on d_out
    ln_rows<768><<<dim3((unsigned)MA, 1, 1), blk, 0, stream>>>(outA, ga, beta_a);
    ln_rows<512><<<dim3((unsigned)MB, 1, 1), blk, 0, stream>>>(outB, gb, beta_b);
}

// Round 2
// 808.495 us; speedup vs baseline: 1.0045x; 1.0045x over previous
//
#include <hip/hip_runtime.h>
#include <stdint.h>

typedef short bf16x8 __attribute__((ext_vector_type(8)));
typedef float f32x4 __attribute__((ext_vector_type(4)));

#define BM 128
#define BN 128
#define BK 64

#define AS1 __attribute__((address_space(1)))
#define AS3 __attribute__((address_space(3)))

__device__ __forceinline__ ushort f2bf(float x) {
    uint32_t u = __float_as_uint(x);
    u += 0x7FFFu + ((u >> 16) & 1u);
    return (ushort)(u >> 16);
}

__device__ __forceinline__ void gload16(const void* g, void* l) {
    __builtin_amdgcn_global_load_lds((const AS1 void*)g, (AS3 void*)l, 16, 0, 0);
}

// C[M,N] = A[M,K] * B[N,K]^T, bf16 MFMA 16x16x32, 128x128 tile, 4 waves.
// Staging: global_load_lds width-16, linear LDS dest, XOR-swizzled global src.
// MODE 0: bf16 out = acc (+bias), optional transposed copy (per-batch [col][row])
// MODE 1: scores: e=exp(tanh(acc)); write E + E^T bf16; atomic rowsum/colsum
// MODE 2: bf16 out = acc / scale[row]
// MODE 3: f32 out = acc + bias[col] + resid[row,col]
template<int MODE, bool A_F32, bool HAS_BIAS, bool WRITE_T>
__global__ __launch_bounds__(256)
void gemm_bt(const void* __restrict__ Aptr_, const ushort* __restrict__ Bptr_,
             void* __restrict__ Cptr_, ushort* __restrict__ CTptr_,
             const float* __restrict__ bias, const float* __restrict__ resid_,
             float* __restrict__ rsum_, float* __restrict__ csum_,
             const float* __restrict__ scale_,
             int M, int N, int K, int lda, int ldb, int ldc,
             long sA, long sB, long sC, long sCT, long sSum,
             int ldct, int rbshift)
{
    __shared__ ushort Alds[BM * BK];
    __shared__ ushort Blds[BN * BK];

    const int z    = blockIdx.z;
    const int m0   = blockIdx.x * BM;
    const int n0   = blockIdx.y * BN;
    const int tid  = threadIdx.x;
    const int lane = tid & 63;
    const int wave = tid >> 6;
    const int wr   = wave >> 1, wc = wave & 1;
    const int g    = lane >> 4, c = lane & 15;

    const ushort* Bp = Bptr_ + z * sB;

    f32x4 acc[4][4] = {};

    for (int kt = 0; kt < K; kt += BK) {
        // ---- stage A and B tiles into LDS ----
        #pragma unroll
        for (int r = 0; r < 4; ++r) {
            const int li  = r * 256 + tid;     // 16B-chunk linear index
            const int row = li >> 3;
            const int ck  = li & 7;
            const int gck = ck ^ (row & 7);    // swizzled source chunk
            if constexpr (A_F32) {
                const float* src = (const float*)Aptr_ + z * sA + (long)(m0 + row) * lda + kt + gck * 8;
                const float4 f0 = *(const float4*)(src);
                const float4 f1 = *(const float4*)(src + 4);
                uint4 w;
                w.x = (uint)f2bf(f0.x) | ((uint)f2bf(f0.y) << 16);
                w.y = (uint)f2bf(f0.z) | ((uint)f2bf(f0.w) << 16);
                w.z = (uint)f2bf(f1.x) | ((uint)f2bf(f1.y) << 16);
                w.w = (uint)f2bf(f1.z) | ((uint)f2bf(f1.w) << 16);
                *(uint4*)&Alds[li * 8] = w;
            } else {
                const ushort* src = (const ushort*)Aptr_ + z * sA + (long)(m0 + row) * lda + kt + gck * 8;
                gload16(src, &Alds[li * 8]);
            }
            const ushort* srcb = Bp + (long)(n0 + row) * ldb + kt + gck * 8;
            gload16(srcb, &Blds[li * 8]);
        }
        __syncthreads();
        #pragma unroll
        for (int kk = 0; kk < 2; ++kk) {
            bf16x8 af[4], bfr[4];
            #pragma unroll
            for (int mi = 0; mi < 4; ++mi) {
                const int row = wr * 64 + mi * 16 + c;
                const int ckq = (kk * 4 + g) ^ (row & 7);
                af[mi] = *(const bf16x8*)&Alds[row * BK + ckq * 8];
            }
            #pragma unroll
            for (int ni = 0; ni < 4; ++ni) {
                const int row = wc * 64 + ni * 16 + c;
                const int ckq = (kk * 4 + g) ^ (row & 7);
                bfr[ni] = *(const bf16x8*)&Blds[row * BK + ckq * 8];
            }
            #pragma unroll
            for (int mi = 0; mi < 4; ++mi)
                #pragma unroll
                for (int ni = 0; ni < 4; ++ni)
                    acc[mi][ni] = __builtin_amdgcn_mfma_f32_16x16x32_bf16(af[mi], bfr[ni], acc[mi][ni], 0, 0, 0);
        }
        __syncthreads();
    }

    // ---- epilogues ----
    if constexpr (MODE == 0) {
        ushort* Cp = (ushort*)Cptr_ + z * sC;
        #pragma unroll
        for (int mi = 0; mi < 4; ++mi) {
            const int row = m0 + wr * 64 + mi * 16 + g * 4;
            #pragma unroll
            for (int ni = 0; ni < 4; ++ni) {
                const int col = n0 + wc * 64 + ni * 16 + c;
                const float bv = HAS_BIAS ? bias[col] : 0.f;
                ushort v[4];
                #pragma unroll
                for (int r = 0; r < 4; ++r) v[r] = f2bf(acc[mi][ni][r] + bv);
                #pragma unroll
                for (int r = 0; r < 4; ++r) Cp[(long)(row + r) * ldc + col] = v[r];
                if constexpr (WRITE_T) {
                    const int bb = row >> rbshift;
                    const int ii = row & ((1 << rbshift) - 1);
                    *(ushort4*)&CTptr_[(long)bb * sCT + (long)col * ldct + ii] =
                        make_ushort4(v[0], v[1], v[2], v[3]);
                }
            }
        }
    } else if constexpr (MODE == 1) {
        ushort* Ep  = (ushort*)Cptr_ + z * sC;
        ushort* ETp = CTptr_ + z * sCT;
        float* rs = rsum_ + z * sSum;
        float* cs = csum_ + z * sSum;
        float rowpart[4][4] = {};
        float colpart[4] = {};
        #pragma unroll
        for (int mi = 0; mi < 4; ++mi) {
            const int row = m0 + wr * 64 + mi * 16 + g * 4;
            #pragma unroll
            for (int ni = 0; ni < 4; ++ni) {
                const int col = n0 + wc * 64 + ni * 16 + c;
                ushort v[4];
                #pragma unroll
                for (int r = 0; r < 4; ++r) {
                    const float s = acc[mi][ni][r];
                    const float t = 1.f - 2.f / (__expf(2.f * s) + 1.f);  // tanh(s)
                    const float e = __expf(t);
                    rowpart[mi][r] += e;
                    colpart[ni]    += e;
                    v[r] = f2bf(e);
                }
                #pragma unroll
                for (int r = 0; r < 4; ++r) Ep[(long)(row + r) * ldc + col] = v[r];
                *(ushort4*)&ETp[(long)col * ldct + row] = make_ushort4(v[0], v[1], v[2], v[3]);
            }
        }
        #pragma unroll
        for (int mi = 0; mi < 4; ++mi) {
            #pragma unroll
            for (int r = 0; r < 4; ++r) {
                float v = rowpart[mi][r];
                v += __shfl_xor(v, 1); v += __shfl_xor(v, 2);
                v += __shfl_xor(v, 4); v += __shfl_xor(v, 8);
                if (c == 0) atomicAdd(&rs[m0 + wr * 64 + mi * 16 + g * 4 + r], v);
            }
        }
        #pragma unroll
        for (int ni = 0; ni < 4; ++ni) {
            float v = colpart[ni];
            v += __shfl_xor(v, 16); v += __shfl_xor(v, 32);
            if (g == 0) atomicAdd(&cs[n0 + wc * 64 + ni * 16 + c], v);
        }
    } else if constexpr (MODE == 2) {
        const float* sc = scale_ + z * sSum;
        ushort* Cp = (ushort*)Cptr_ + z * sC;
        #pragma unroll
        for (int mi = 0; mi < 4; ++mi) {
            const int row = m0 + wr * 64 + mi * 16 + g * 4;
            float rcp[4];
            #pragma unroll
            for (int r = 0; r < 4; ++r) rcp[r] = 1.f / sc[row + r];
            #pragma unroll
            for (int ni = 0; ni < 4; ++ni) {
                const int col = n0 + wc * 64 + ni * 16 + c;
                #pragma unroll
                for (int r = 0; r < 4; ++r)
                    Cp[(long)(row + r) * ldc + col] = f2bf(acc[mi][ni][r] * rcp[r]);
            }
        }
    } else { // MODE == 3
        float* Co = (float*)Cptr_;
        #pragma unroll
        for (int mi = 0; mi < 4; ++mi) {
            const int row = m0 + wr * 64 + mi * 16 + g * 4;
            #pragma unroll
            for (int ni = 0; ni < 4; ++ni) {
                const int col = n0 + wc * 64 + ni * 16 + c;
                const float bv = bias[col];
                #pragma unroll
                for (int r = 0; r < 4; ++r) {
                    const long idx = (long)(row + r) * ldc + col;
                    Co[idx] = acc[mi][ni][r] + bv + resid_[idx];
                }
            }
        }
    }
}

// f32 [R][C] -> bf16 [C][R]
__global__ __launch_bounds__(256)
void tcast(const float* __restrict__ in, ushort* __restrict__ out, int R, int C) {
    __shared__ float t[32][33];
    const int bx = blockIdx.x * 32, by = blockIdx.y * 32;
    const int tx = threadIdx.x, ty = threadIdx.y; // (32, 8)
    for (int i = ty; i < 32; i += 8) {
        const int r = by + i, cc = bx + tx;
        if (r < R && cc < C) t[i][tx] = in[(long)r * C + cc];
    }
    __syncthreads();
    for (int i = ty; i < 32; i += 8) {
        const int cc = bx + i, r = by + tx;
        if (cc < C && r < R) out[(long)cc * R + r] = f2bf(t[tx][i]);
    }
}

// in-place LayerNorm, one row per block
template<int D>
__global__ __launch_bounds__(256)
void ln_rows(float* __restrict__ y, const float* __restrict__ gam, const float* __restrict__ bet) {
    constexpr int NV = D / 256;
    const long row = blockIdx.x;
    float* p = y + row * D;
    const int tid = threadIdx.x;
    float v[NV];
    float s = 0.f, s2 = 0.f;
    #pragma unroll
    for (int k = 0; k < NV; ++k) {
        v[k] = p[tid + k * 256];
        s += v[k]; s2 += v[k] * v[k];
    }
    #pragma unroll
    for (int off = 1; off < 64; off <<= 1) {
        s  += __shfl_xor(s, off);
        s2 += __shfl_xor(s2, off);
    }
    __shared__ float ws[4], ws2[4];
    const int wave = tid >> 6, lane = tid & 63;
    if (lane == 0) { ws[wave] = s; ws2[wave] = s2; }
    __syncthreads();
    s  = ws[0] + ws[1] + ws[2] + ws[3];
    s2 = ws2[0] + ws2[1] + ws2[2] + ws2[3];
    const float mu  = s / D;
    const float var = s2 / D - mu * mu;
    const float rstd = rsqrtf(var + 1e-5f);
    #pragma unroll
    for (int k = 0; k < NV; ++k) {
        const int i = tid + k * 256;
        p[i] = (v[k] - mu) * rstd * gam[i] + bet[i];
    }
}

extern "C" void kernel_launch(void* const* d_in, const int* in_sizes, int n_in,
                              void* d_out, int out_size, void* d_ws, size_t ws_size,
                              hipStream_t stream)
{
    (void)in_sizes; (void)n_in; (void)out_size; (void)ws_size;
    const float* z_a    = (const float*)d_in[0];
    const float* z_b    = (const float*)d_in[1];
    const float* Wa     = (const float*)d_in[2];
    const float* ba     = (const float*)d_in[3];
    const float* Wb     = (const float*)d_in[4];
    const float* bb     = (const float*)d_in[5];
    const float* Wco    = (const float*)d_in[6];
    const float* Woa    = (const float*)d_in[7];
    const float* boa    = (const float*)d_in[8];
    const float* Wob    = (const float*)d_in[9];
    const float* bob    = (const float*)d_in[10];
    const float* ga     = (const float*)d_in[11];
    const float* beta_a = (const float*)d_in[12];
    const float* gb     = (const float*)d_in[13];
    const float* beta_b = (const float*)d_in[14];

    const int Bn = 16, LA = 2048, LB = 2048, DA = 768, DB = 512, DH = 512;
    const long MA = (long)Bn * LA;  // 32768 flattened rows for a-side
    const long MB = (long)Bn * LB;

    char* w = (char*)d_ws;
    size_t off = 0;
    auto alc = [&](size_t bytes) { void* p = w + off; off += (bytes + 255) & ~(size_t)255; return p; };

    ushort* WaT  = (ushort*)alc((size_t)DH * DA * 2);
    ushort* WbT  = (ushort*)alc((size_t)DH * DB * 2);
    ushort* WcoT = (ushort*)alc((size_t)DH * DH * 2);
    ushort* WoaT = (ushort*)alc((size_t)DA * DH * 2);
    ushort* WobT = (ushort*)alc((size_t)DB * DH * 2);
    ushort* h_a  = (ushort*)alc((size_t)MA * DH * 2);
    ushort* h_b  = (ushort*)alc((size_t)MB * DH * 2);
    ushort* h_aT = (ushort*)alc((size_t)Bn * DH * LA * 2);
    ushort* h_bT = (ushort*)alc((size_t)Bn * DH * LB * 2);
    ushort* Ma   = (ushort*)alc((size_t)MA * DH * 2);
    ushort* E    = (ushort*)alc((size_t)Bn * LA * LB * 2);
    ushort* ET   = (ushort*)alc((size_t)Bn * LB * LA * 2);
    ushort* Pa   = (ushort*)alc((size_t)MA * DH * 2);
    ushort* Pb   = (ushort*)alc((size_t)MB * DH * 2);
    float*  rsum = (float*)alc((size_t)Bn * LA * 4);
    float*  csum = (float*)alc((size_t)Bn * LB * 4);

    dim3 blk(256, 1, 1);
    dim3 tb(32, 8, 1);

    // weight transposes (f32 -> bf16, [K][N] -> [N][K])
    tcast<<<dim3(DH / 32, DA / 32, 1), tb, 0, stream>>>(Wa,  WaT,  DA, DH);
    tcast<<<dim3(DH / 32, DB / 32, 1), tb, 0, stream>>>(Wb,  WbT,  DB, DH);
    tcast<<<dim3(DH / 32, DH / 32, 1), tb, 0, stream>>>(Wco, WcoT, DH, DH);
    tcast<<<dim3(DA / 32, DH / 32, 1), tb, 0, stream>>>(Woa, WoaT, DH, DA);
    tcast<<<dim3(DB / 32, DH / 32, 1), tb, 0, stream>>>(Wob, WobT, DH, DB);

    // zero softmax denominators (rsum & csum are contiguous)
    hipMemsetAsync(rsum, 0, (size_t)Bn * (LA + LB) * sizeof(float), stream);

    // h_a = z_a @ Wa + ba   (also writes h_aT per batch)
    gemm_bt<0, true, true, true><<<dim3(MA / BM, DH / BN, 1), blk, 0, stream>>>(
        z_a, WaT, h_a, h_aT, ba, nullptr, nullptr, nullptr, nullptr,
        (int)MA, DH, DA, DA, DA, DH, 0, 0, 0, (long)DH * LA, 0, LA, 11);

    // h_b = z_b @ Wb + bb   (also writes h_bT per batch)
    gemm_bt<0, true, true, true><<<dim3(MB / BM, DH / BN, 1), blk, 0, stream>>>(
        z_b, WbT, h_b, h_bT, bb, nullptr, nullptr, nullptr, nullptr,
        (int)MB, DH, DB, DB, DB, DH, 0, 0, 0, (long)DH * LB, 0, LB, 11);

    // Ma = h_a @ W_co
    gemm_bt<0, false, false, false><<<dim3(MA / BM, DH / BN, 1), blk, 0, stream>>>(
        h_a, WcoT, Ma, nullptr, nullptr, nullptr, nullptr, nullptr, nullptr,
        (int)MA, DH, DH, DH, DH, DH, 0, 0, 0, 0, 0, 0, 0);

    // scores: E = exp(tanh(Ma @ h_b^T)), E^T, rowsum, colsum  (batched)
    gemm_bt<1, false, false, false><<<dim3(LA / BM, LB / BN, Bn), blk, 0, stream>>>(
        Ma, h_b, E, ET, nullptr, nullptr, rsum, csum, nullptr,
        LA, LB, DH, DH, DH, LB,
        (long)LA * DH, (long)LB * DH, (long)LA * LB, (long)LB * LA, LA, LA, 0);

    // Pa = (E @ h_b) / rowsum  (batched)
    gemm_bt<2, false, false, false><<<dim3(LA / BM, DH / BN, Bn), blk, 0, stream>>>(
        E, h_bT, Pa, nullptr, nullptr, nullptr, nullptr, nullptr, rsum,
        LA, DH, LB, LB, LB, DH,
        (long)LA * LB, (long)DH * LB, (long)LA * DH, 0, LA, 0, 0);

    // Pb = (E^T @ h_a) / colsum  (batched)
    gemm_bt<2, false, false, false><<<dim3(LB / BM, DH / BN, Bn), blk, 0, stream>>>(
        ET, h_aT, Pb, nullptr, nullptr, nullptr, nullptr, nullptr, csum,
        LB, DH, LA, LA, LA, DH,
        (long)LB * LA, (long)DH * LA, (long)LB * DH, 0, LB, 0, 0);

    float* outA = (float*)d_out;
    float* outB = outA + MA * DA;

    // z_a_pre = Pa @ Woa + boa + z_a  -> d_out (f32, in place for LN)
    gemm_bt<3, false, true, false><<<dim3(MA / BM, DA / BN, 1), blk, 0, stream>>>(
        Pa, WoaT, outA, nullptr, boa, z_a, nullptr, nullptr, nullptr,
        (int)MA, DA, DH, DH, DH, DA, 0, 0, 0, 0, 0, 0, 0);

    // z_b_pre = Pb @ Wob + bob + z_b  -> d_out
    gemm_bt<3, false, true, false><<<dim3(MB / BM, DB / BN, 1), blk, 0, stream>>>(
        Pb, WobT, outB, nullptr, bob, z_b, nullptr, nullptr, nullptr,
        (int)MB, DB, DH, DH, DH, DB, 0, 0, 0, 0, 0, 0, 0);

    // LayerNorms in place on d_out
    ln_rows<768><<<dim3((unsigned)MA, 1, 1), blk, 0, stream>>>(outA, ga, beta_a);
    ln_rows<512><<<dim3((unsigned)MB, 1, 1), blk, 0, stream>>>(outB, gb, beta_b);
}